// Round 19
// baseline (564.661 us; speedup 1.0000x reference)
//
#include <hip/hip_runtime.h>
#include <hip/hip_bf16.h>
#include <math.h>

#define GH 721
#define GW 1440
#define C_IN 78
#define NNODES 5882
#define KNEIGH 128
#define M_TOTAL (NNODES * KNEIGH)   // 752896
#define TM 64
#define NBLOCKS (M_TOTAL / TM)      // 11764

typedef __attribute__((ext_vector_type(8))) short bf16x8;
typedef __attribute__((ext_vector_type(4))) float f32x4;

__device__ __forceinline__ unsigned short f2bf(float x) {
    __hip_bfloat16 b = __float2bfloat16(x);
    union { __hip_bfloat16 h; unsigned short u; } cv; cv.h = b; return cv.u;
}

// ---------------- prep kernel (unchanged from R11) ----------------
__global__ void prep_kernel(const float* __restrict__ W1, const float* __restrict__ W2,
                            const float* __restrict__ means, const float* __restrict__ stds,
                            const float* __restrict__ b1, const float* __restrict__ lnS,
                            const float* __restrict__ lnO, const float* __restrict__ b2,
                            unsigned short* __restrict__ bp1, unsigned short* __restrict__ bp2,
                            float* __restrict__ latT, float* __restrict__ lonT,
                            float* __restrict__ b1p, float* __restrict__ K1,
                            float* __restrict__ K2)
{
    const int NB1 = 3 * 4 * 256 * 8;   // 24576
    const int NB2 = 8 * 4 * 256 * 8;   // 65536
    const int NTOT = NB1 + NB2 + GH + GW + 256;
    for (int e = blockIdx.x * blockDim.x + threadIdx.x; e < NTOT;
         e += gridDim.x * blockDim.x) {
        if (e < NB1) {
            int j = e & 7, c = (e >> 3) & 255, o = (e >> 11) & 3, s = e >> 13;
            int k = s * 32 + o * 8 + j;
            float v = 0.f;
            if (k < 82) v = W1[k * 256 + c] / (stds[k] + 1e-7f);
            bp1[e] = f2bf(v);
        } else if (e < NB1 + NB2) {
            int t = e - NB1;
            int j = t & 7, c = (t >> 3) & 255, o = (t >> 11) & 3, s = t >> 13;
            int k = s * 32 + o * 8 + j;
            bp2[t] = f2bf(W2[k * 256 + c] * lnS[k]);
        } else if (e < NB1 + NB2 + GH) {
            int h = e - NB1 - NB2;
            float r = (-90.f + 0.25f * (float)h) * 0.017453292519943295f;
            latT[2 * h]     = sinf(r);
            latT[2 * h + 1] = cosf(r);
        } else if (e < NB1 + NB2 + GH + GW) {
            int w = e - NB1 - NB2 - GH;
            float r = ((float)w * (360.f / 1439.f)) * 0.017453292519943295f;
            lonT[2 * w]     = sinf(r);
            lonT[2 * w + 1] = cosf(r);
        } else {
            int c = e - NB1 - NB2 - GH - GW;   // output/hidden column 0..255
            float acc = b1[c];
            #pragma unroll 1
            for (int k = 0; k < 86; ++k) {
                float inv = 1.f / (stds[k] + 1e-7f);
                float w = W1[k * 256 + c] * inv;
                acc -= means[k] * w;
                if (k == 82) acc += 0.5f * w;   // day-of-year channel, raw value 0.5
            }
            b1p[c] = acc;
            float k1 = 0.f, k2 = 0.f;
            #pragma unroll 1
            for (int k = 0; k < 256; ++k) {
                float w = W2[k * 256 + c];
                k1 += lnS[k] * w;
                k2 += lnO[k] * w;
            }
            K1[c] = k1;
            K2[c] = k2 + b2[c];
        }
    }
}

// Build one A-fragment (8 channels of one row) directly from global memory.
// c0 in {0,8,...,88}; channels 78/79=lat, 80/81=lon, 82..95=0 (folded/pad).
__device__ __forceinline__ bf16x8 make_af(const float* __restrict__ var_grid,
                                          const float* __restrict__ latT,
                                          const float* __restrict__ lonT,
                                          int idx, int hh, int ww, int c0)
{
    float v[8];
    const float* src = var_grid + (size_t)idx * C_IN;
    if (c0 < 72) {                      // all 8 channels from the grid (8-B aligned)
        #pragma unroll
        for (int j = 0; j < 4; ++j) {
            float2 t = *(const float2*)(src + c0 + 2 * j);
            v[2 * j] = t.x; v[2 * j + 1] = t.y;
        }
    } else if (c0 == 72) {              // 72..77 grid, 78..79 lat sin/cos
        #pragma unroll
        for (int j = 0; j < 3; ++j) {
            float2 t = *(const float2*)(src + 72 + 2 * j);
            v[2 * j] = t.x; v[2 * j + 1] = t.y;
        }
        v[6] = latT[2 * hh]; v[7] = latT[2 * hh + 1];
    } else if (c0 == 80) {              // 80..81 lon sin/cos, rest folded->0
        v[0] = lonT[2 * ww]; v[1] = lonT[2 * ww + 1];
        #pragma unroll
        for (int j = 2; j < 8; ++j) v[j] = 0.f;
    } else {                            // 88..95 pad
        #pragma unroll
        for (int j = 0; j < 8; ++j) v[j] = 0.f;
    }
    bf16x8 r;
    #pragma unroll
    for (int j = 0; j < 8; ++j) r[j] = (short)f2bf(v[j]);
    return r;
}

// ---------------- fused kernel: direct-A GEMM1 (no x_lds, no pack, ONE barrier) ----
// Each lane loads its own A-fragment channels straight from var_grid (same bf16
// rounding as the packed path). Removes the gather->pack->LDS->barrier serial
// head entirely. A-rows read 4x across col-quarter waves (L1/L2 broadcast).
__global__ __launch_bounds__(512, 4)
void fused_kernel(const float* __restrict__ var_grid, const int* __restrict__ idxs,
                  const unsigned short* __restrict__ bp1, const unsigned short* __restrict__ bp2,
                  const float* __restrict__ latT, const float* __restrict__ lonT,
                  const float* __restrict__ b1p, const float* __restrict__ K1,
                  const float* __restrict__ K2,
                  float* __restrict__ out)
{
    __shared__ __align__(16) unsigned short h_lds[TM * 256];  // 32768 B, XOR-swizzled
    __shared__ float red[2][4][TM];                           // 2048 B

    // Bijective XCD-aware swizzle (nwg=11764, q=1470, r=4)
    const int q_ = 1470, r_ = 4;
    const int xcd = blockIdx.x & 7;
    const int ii  = blockIdx.x >> 3;
    const int swz = (xcd < r_ ? xcd * (q_ + 1) : r_ * (q_ + 1) + (xcd - r_) * q_) + ii;

    const int tid  = threadIdx.x;
    const int lane = tid & 63;
    const int wave = tid >> 6;       // 0..7
    const int wr   = wave >> 2;      // 0..1  row half (32 rows)
    const int wc   = wave & 3;       // 0..3  col quarter (64 cols)
    const int l15  = lane & 15;
    const int lg   = lane >> 4;      // 0..3
    const int wbase = wc * 64;
    const int rbase = wr * 32;
    const long block0 = (long)swz * TM;

    // per-thread weight-fragment base pointers
    const unsigned short* bp1t = bp1 + ((size_t)(lg * 256) + wbase + l15) * 8;
    const unsigned short* bp2t = bp2 + ((size_t)(lg * 256) + wbase + l15) * 8;

    // per-lane A-row indices (held through GEMM1 only: 6 regs)
    int idxA[2], hhA[2], wwA[2];
    #pragma unroll
    for (int mf = 0; mf < 2; ++mf) {
        idxA[mf] = idxs[block0 + rbase + mf * 16 + l15];
        hhA[mf]  = idxA[mf] / GW;
        wwA[mf]  = idxA[mf] - hhA[mf] * GW;
    }

    float b1v[4];
    #pragma unroll
    for (int nf = 0; nf < 4; ++nf) b1v[nf] = b1p[wbase + nf * 16 + l15];

    // ---- GEMM1: A direct from global, bw prefetched one step ahead ----
    f32x4 acc[2][4];
    #pragma unroll
    for (int mf = 0; mf < 2; ++mf)
        #pragma unroll
        for (int nf = 0; nf < 4; ++nf) acc[mf][nf] = (f32x4){0.f, 0.f, 0.f, 0.f};

    bf16x8 bw[4], bwn[4];
    #pragma unroll
    for (int nf = 0; nf < 4; ++nf)
        bw[nf] = *(const bf16x8*)(bp1t + ((size_t)nf * 16) * 8);

    #pragma unroll
    for (int s = 0; s < 3; ++s) {
        if (s < 2)
            #pragma unroll
            for (int nf = 0; nf < 4; ++nf)
                bwn[nf] = *(const bf16x8*)(bp1t + ((size_t)(s + 1) * 4 * 256 + nf * 16) * 8);
        bf16x8 af[2];
        #pragma unroll
        for (int mf = 0; mf < 2; ++mf)
            af[mf] = make_af(var_grid, latT, lonT, idxA[mf], hhA[mf], wwA[mf],
                             s * 32 + lg * 8);
        #pragma unroll
        for (int mf = 0; mf < 2; ++mf)
            #pragma unroll
            for (int nf = 0; nf < 4; ++nf)
                acc[mf][nf] = __builtin_amdgcn_mfma_f32_16x16x32_bf16(af[mf], bw[nf], acc[mf][nf], 0, 0, 0);
        #pragma unroll
        for (int nf = 0; nf < 4; ++nf) bw[nf] = bwn[nf];
    }

    // ---- bias + ReLU -> h (bf16, swizzled) + row-stat partials ----
    float sm[2][4], sq[2][4];
    #pragma unroll
    for (int mf = 0; mf < 2; ++mf)
        #pragma unroll
        for (int i = 0; i < 4; ++i) { sm[mf][i] = 0.f; sq[mf][i] = 0.f; }

    #pragma unroll
    for (int mf = 0; mf < 2; ++mf)
        #pragma unroll
        for (int nf = 0; nf < 4; ++nf)
            #pragma unroll
            for (int i = 0; i < 4; ++i) {
                float v = fmaxf(acc[mf][nf][i] + b1v[nf], 0.f);
                sm[mf][i] += v;
                sq[mf][i] += v * v;
                int row = rbase + mf * 16 + lg * 4 + i;
                int col = wbase + nf * 16 + l15;
                unsigned off = (unsigned)(row * 512 + col * 2);
                off ^= (unsigned)((row & 7) << 4);
                *(unsigned short*)((char*)h_lds + off) = f2bf(v);
            }

    #pragma unroll
    for (int m = 1; m < 16; m <<= 1)
        #pragma unroll
        for (int mf = 0; mf < 2; ++mf)
            #pragma unroll
            for (int i = 0; i < 4; ++i) {
                sm[mf][i] += __shfl_xor(sm[mf][i], m, 64);
                sq[mf][i] += __shfl_xor(sq[mf][i], m, 64);
            }

    if (l15 == 0) {
        #pragma unroll
        for (int mf = 0; mf < 2; ++mf)
            #pragma unroll
            for (int i = 0; i < 4; ++i) {
                int row = rbase + mf * 16 + lg * 4 + i;
                red[0][wc][row] = sm[mf][i];
                red[1][wc][row] = sq[mf][i];
            }
    }

    // prefetch GEMM2 step-0 weights BEFORE the barrier
    #pragma unroll
    for (int nf = 0; nf < 4; ++nf)
        bw[nf] = *(const bf16x8*)(bp2t + ((size_t)nf * 16) * 8);

    __syncthreads();   // the ONLY barrier: h + red visible

    // ---- GEMM2: h[64x256] @ W2'[256x256], bw prefetched one step ahead ----
    #pragma unroll
    for (int mf = 0; mf < 2; ++mf)
        #pragma unroll
        for (int nf = 0; nf < 4; ++nf) acc[mf][nf] = (f32x4){0.f, 0.f, 0.f, 0.f};

    #pragma unroll
    for (int s = 0; s < 8; ++s) {
        if (s < 7)
            #pragma unroll
            for (int nf = 0; nf < 4; ++nf)
                bwn[nf] = *(const bf16x8*)(bp2t + ((size_t)(s + 1) * 4 * 256 + nf * 16) * 8);
        bf16x8 af[2];
        #pragma unroll
        for (int mf = 0; mf < 2; ++mf) {
            int row = rbase + mf * 16 + l15;
            unsigned off = (unsigned)(row * 512 + (s * 32 + lg * 8) * 2);
            off ^= (unsigned)((row & 7) << 4);
            af[mf] = *(const bf16x8*)((char*)h_lds + off);
        }
        #pragma unroll
        for (int mf = 0; mf < 2; ++mf)
            #pragma unroll
            for (int nf = 0; nf < 4; ++nf)
                acc[mf][nf] = __builtin_amdgcn_mfma_f32_16x16x32_bf16(af[mf], bw[nf], acc[mf][nf], 0, 0, 0);
        #pragma unroll
        for (int nf = 0; nf < 4; ++nf) bw[nf] = bwn[nf];
    }

    // ---- epilogue: LN applied algebraically; direct plain stores ----
    float K1v[4], K2v[4];
    #pragma unroll
    for (int nf = 0; nf < 4; ++nf) {
        int col = wbase + nf * 16 + l15;
        K1v[nf] = K1[col]; K2v[nf] = K2[col];
    }
    #pragma unroll
    for (int mf = 0; mf < 2; ++mf)
        #pragma unroll
        for (int i = 0; i < 4; ++i) {
            int row = rbase + mf * 16 + lg * 4 + i;
            float tot = red[0][0][row] + red[0][1][row] + red[0][2][row] + red[0][3][row];
            float tq  = red[1][0][row] + red[1][1][row] + red[1][2][row] + red[1][3][row];
            float mean = tot * (1.f / 256.f);
            float var  = tq * (1.f / 256.f) - mean * mean;
            float rs = rsqrtf(var + 1e-5f);
            long row_g = block0 + row;
            float* po = out + row_g * 256 + wbase;
            #pragma unroll
            for (int nf = 0; nf < 4; ++nf)
                po[nf * 16 + l15] = rs * (acc[mf][nf][i] - mean * K1v[nf]) + K2v[nf];
        }
}

extern "C" void kernel_launch(void* const* d_in, const int* in_sizes, int n_in,
                              void* d_out, int out_size, void* d_ws, size_t ws_size,
                              hipStream_t stream) {
    const float* var_grid = (const float*)d_in[0];
    const int*   idxs     = (const int*)d_in[1];
    const float* means    = (const float*)d_in[2];
    const float* stds     = (const float*)d_in[3];
    const float* W1       = (const float*)d_in[4];
    const float* b1       = (const float*)d_in[5];
    const float* lnS      = (const float*)d_in[6];
    const float* lnO      = (const float*)d_in[7];
    const float* W2       = (const float*)d_in[8];
    const float* b2       = (const float*)d_in[9];
    float* out = (float*)d_out;

    char* ws = (char*)d_ws;
    unsigned short* bp1 = (unsigned short*)ws;               // 49152 B
    unsigned short* bp2 = (unsigned short*)(ws + 49152);     // 131072 B -> 180224
    float* latT = (float*)(ws + 180224);                     // 5768 B
    float* lonT = (float*)(ws + 186000);                     // 11520 B
    float* b1p  = (float*)(ws + 197520);                     // 1024 B
    float* K1   = (float*)(ws + 198544);                     // 1024 B
    float* K2   = (float*)(ws + 199568);                     // 1024 B (end 200592)

    prep_kernel<<<362, 256, 0, stream>>>(W1, W2, means, stds, b1, lnS, lnO, b2,
                                         bp1, bp2, latT, lonT, b1p, K1, K2);
    fused_kernel<<<NBLOCKS, 512, 0, stream>>>(var_grid, idxs, bp1, bp2, latT, lonT,
                                              b1p, K1, K2, out);
}

// Round 20
// 426.042 us; speedup vs baseline: 1.3254x; 1.3254x over previous
//
#include <hip/hip_runtime.h>
#include <hip/hip_bf16.h>
#include <math.h>

#define GH 721
#define GW 1440
#define C_IN 78
#define NNODES 5882
#define KNEIGH 128
#define M_TOTAL (NNODES * KNEIGH)   // 752896
#define TM 64
#define NBLOCKS (M_TOTAL / TM)      // 11764

typedef __attribute__((ext_vector_type(8))) short bf16x8;
typedef __attribute__((ext_vector_type(4))) float f32x4;

__device__ __forceinline__ unsigned short f2bf(float x) {
    __hip_bfloat16 b = __float2bfloat16(x);
    union { __hip_bfloat16 h; unsigned short u; } cv; cv.h = b; return cv.u;
}

// ---------------- prep kernel ----------------
// bp1: [3][4][256][8] bf16 = W1 * inv_std (rows >=82 zero; constants folded into b1p)
// bp2: [8][4][256][8] bf16 = lnS[k] * W2[k,e]   (LN scale folded into W2)
// K1[e] = sum_k lnS[k]*W2[k,e];  K2[e] = sum_k lnO[k]*W2[k,e] + b2[e]
__global__ void prep_kernel(const float* __restrict__ W1, const float* __restrict__ W2,
                            const float* __restrict__ means, const float* __restrict__ stds,
                            const float* __restrict__ b1, const float* __restrict__ lnS,
                            const float* __restrict__ lnO, const float* __restrict__ b2,
                            unsigned short* __restrict__ bp1, unsigned short* __restrict__ bp2,
                            float* __restrict__ latT, float* __restrict__ lonT,
                            float* __restrict__ b1p, float* __restrict__ K1,
                            float* __restrict__ K2)
{
    const int NB1 = 3 * 4 * 256 * 8;   // 24576
    const int NB2 = 8 * 4 * 256 * 8;   // 65536
    const int NTOT = NB1 + NB2 + GH + GW + 256;
    for (int e = blockIdx.x * blockDim.x + threadIdx.x; e < NTOT;
         e += gridDim.x * blockDim.x) {
        if (e < NB1) {
            int j = e & 7, c = (e >> 3) & 255, o = (e >> 11) & 3, s = e >> 13;
            int k = s * 32 + o * 8 + j;
            float v = 0.f;
            if (k < 82) v = W1[k * 256 + c] / (stds[k] + 1e-7f);
            bp1[e] = f2bf(v);
        } else if (e < NB1 + NB2) {
            int t = e - NB1;
            int j = t & 7, c = (t >> 3) & 255, o = (t >> 11) & 3, s = t >> 13;
            int k = s * 32 + o * 8 + j;
            bp2[t] = f2bf(W2[k * 256 + c] * lnS[k]);
        } else if (e < NB1 + NB2 + GH) {
            int h = e - NB1 - NB2;
            float r = (-90.f + 0.25f * (float)h) * 0.017453292519943295f;
            latT[2 * h]     = sinf(r);
            latT[2 * h + 1] = cosf(r);
        } else if (e < NB1 + NB2 + GH + GW) {
            int w = e - NB1 - NB2 - GH;
            float r = ((float)w * (360.f / 1439.f)) * 0.017453292519943295f;
            lonT[2 * w]     = sinf(r);
            lonT[2 * w + 1] = cosf(r);
        } else {
            int c = e - NB1 - NB2 - GH - GW;   // output/hidden column 0..255
            float acc = b1[c];
            #pragma unroll 1
            for (int k = 0; k < 86; ++k) {
                float inv = 1.f / (stds[k] + 1e-7f);
                float w = W1[k * 256 + c] * inv;
                acc -= means[k] * w;
                if (k == 82) acc += 0.5f * w;   // day-of-year channel, raw value 0.5
            }
            b1p[c] = acc;
            float k1 = 0.f, k2 = 0.f;
            #pragma unroll 1
            for (int k = 0; k < 256; ++k) {
                float w = W2[k * 256 + c];
                k1 += lnS[k] * w;
                k2 += lnO[k] * w;
            }
            K1[c] = k1;
            K2[c] = k2 + b2[c];
        }
    }
}

// ---------------- fused kernel: best-measured structure (R18, 426.8 us) ----------------
// Wave tile 32x64, acc[2][4]=32 regs; ~112 unified regs < 128 cap -> 16 waves/CU,
// zero spill (WRITE == output exactly). Separate x_lds (no alias barrier), LN folded
// into epilogue, bw one-step prefetch, XCD-swizzled blocks.
__global__ __launch_bounds__(512, 4)
void fused_kernel(const float* __restrict__ var_grid, const int* __restrict__ idxs,
                  const unsigned short* __restrict__ bp1, const unsigned short* __restrict__ bp2,
                  const float* __restrict__ latT, const float* __restrict__ lonT,
                  const float* __restrict__ b1p, const float* __restrict__ K1,
                  const float* __restrict__ K2,
                  float* __restrict__ out)
{
    __shared__ __align__(16) unsigned short x_lds[TM][104];   // 13312 B
    __shared__ __align__(16) unsigned short h_lds[TM * 256];  // 32768 B, XOR-swizzled
    __shared__ float red[2][4][TM];                           // 2048 B

    // Bijective XCD-aware swizzle (nwg=11764, q=1470, r=4)
    const int q_ = 1470, r_ = 4;
    const int xcd = blockIdx.x & 7;
    const int ii  = blockIdx.x >> 3;
    const int swz = (xcd < r_ ? xcd * (q_ + 1) : r_ * (q_ + 1) + (xcd - r_) * q_) + ii;

    const int tid  = threadIdx.x;
    const int lane = tid & 63;
    const int wave = tid >> 6;       // 0..7
    const int wr   = wave >> 2;      // 0..1  row half (32 rows)
    const int wc   = wave & 3;       // 0..3  col quarter (64 cols)
    const int l15  = lane & 15;
    const int lg   = lane >> 4;      // 0..3
    const int wbase = wc * 64;
    const int rbase = wr * 32;
    const long block0 = (long)swz * TM;

    // per-thread weight-fragment base pointers (compile-time step offsets fold in)
    const unsigned short* bp1t = bp1 + ((size_t)(lg * 256) + wbase + l15) * 8;
    const unsigned short* bp2t = bp2 + ((size_t)(lg * 256) + wbase + l15) * 8;

    // ---- gather: 8 lanes/row, batch loads -> regs, pack -> LDS ----
    {
        const int row = tid >> 3, p = tid & 7;     // rows 0..63
        const int idx = idxs[block0 + row];
        const int hh = idx / GW;
        const int ww = idx - hh * GW;
        const float* src = var_grid + (long)idx * C_IN;
        float2 g[5], tl, tl2;
        #pragma unroll
        for (int t = 0; t < 5; ++t) {
            const int q = p + 8 * t;
            if (q < 39) g[t] = *(const float2*)(src + 2 * q);
        }
        tl.x  = latT[2 * hh]; tl.y  = latT[2 * hh + 1];
        tl2.x = lonT[2 * ww]; tl2.y = lonT[2 * ww + 1];
        unsigned int* xrow = (unsigned int*)&x_lds[row][0];
        #pragma unroll
        for (int t = 0; t < 6; ++t) {
            const int q = p + 8 * t;
            float v0, v1;
            if (q < 39)      { v0 = g[t].x; v1 = g[t].y; }
            else if (q == 39){ v0 = tl.x;  v1 = tl.y; }
            else if (q == 40){ v0 = tl2.x; v1 = tl2.y; }
            else             { v0 = 0.f; v1 = 0.f; }   // ch 82..95 folded / pad
            xrow[q] = ((unsigned int)f2bf(v1) << 16) | (unsigned int)f2bf(v0);
        }
    }

    float b1v[4];
    #pragma unroll
    for (int nf = 0; nf < 4; ++nf) b1v[nf] = b1p[wbase + nf * 16 + l15];
    __syncthreads();   // barrier 1: x visible

    // ---- GEMM1: x[64x96] @ W1'[96x256], bw prefetched one step ahead ----
    f32x4 acc[2][4];
    #pragma unroll
    for (int mf = 0; mf < 2; ++mf)
        #pragma unroll
        for (int nf = 0; nf < 4; ++nf) acc[mf][nf] = (f32x4){0.f, 0.f, 0.f, 0.f};

    bf16x8 bw[4], bwn[4];
    #pragma unroll
    for (int nf = 0; nf < 4; ++nf)
        bw[nf] = *(const bf16x8*)(bp1t + ((size_t)nf * 16) * 8);

    #pragma unroll
    for (int s = 0; s < 3; ++s) {
        if (s < 2)
            #pragma unroll
            for (int nf = 0; nf < 4; ++nf)
                bwn[nf] = *(const bf16x8*)(bp1t + ((size_t)(s + 1) * 4 * 256 + nf * 16) * 8);
        bf16x8 af[2];
        #pragma unroll
        for (int mf = 0; mf < 2; ++mf)
            af[mf] = *(const bf16x8*)&x_lds[rbase + mf * 16 + l15][s * 32 + lg * 8];
        #pragma unroll
        for (int mf = 0; mf < 2; ++mf)
            #pragma unroll
            for (int nf = 0; nf < 4; ++nf)
                acc[mf][nf] = __builtin_amdgcn_mfma_f32_16x16x32_bf16(af[mf], bw[nf], acc[mf][nf], 0, 0, 0);
        #pragma unroll
        for (int nf = 0; nf < 4; ++nf) bw[nf] = bwn[nf];
    }

    // ---- bias + ReLU -> h (own columns; x untouched -> no barrier needed) ----
    float sm[2][4], sq[2][4];
    #pragma unroll
    for (int mf = 0; mf < 2; ++mf)
        #pragma unroll
        for (int i = 0; i < 4; ++i) { sm[mf][i] = 0.f; sq[mf][i] = 0.f; }

    #pragma unroll
    for (int mf = 0; mf < 2; ++mf)
        #pragma unroll
        for (int nf = 0; nf < 4; ++nf)
            #pragma unroll
            for (int i = 0; i < 4; ++i) {
                float v = fmaxf(acc[mf][nf][i] + b1v[nf], 0.f);
                sm[mf][i] += v;
                sq[mf][i] += v * v;
                int row = rbase + mf * 16 + lg * 4 + i;
                int col = wbase + nf * 16 + l15;
                unsigned off = (unsigned)(row * 512 + col * 2);
                off ^= (unsigned)((row & 7) << 4);
                *(unsigned short*)((char*)h_lds + off) = f2bf(v);
            }

    #pragma unroll
    for (int m = 1; m < 16; m <<= 1)
        #pragma unroll
        for (int mf = 0; mf < 2; ++mf)
            #pragma unroll
            for (int i = 0; i < 4; ++i) {
                sm[mf][i] += __shfl_xor(sm[mf][i], m, 64);
                sq[mf][i] += __shfl_xor(sq[mf][i], m, 64);
            }

    if (l15 == 0) {
        #pragma unroll
        for (int mf = 0; mf < 2; ++mf)
            #pragma unroll
            for (int i = 0; i < 4; ++i) {
                int row = rbase + mf * 16 + lg * 4 + i;
                red[0][wc][row] = sm[mf][i];
                red[1][wc][row] = sq[mf][i];
            }
    }

    // prefetch GEMM2 step-0 weights BEFORE the barrier (hides under barrier wait)
    #pragma unroll
    for (int nf = 0; nf < 4; ++nf)
        bw[nf] = *(const bf16x8*)(bp2t + ((size_t)nf * 16) * 8);

    __syncthreads();   // barrier 2: h + red visible

    // ---- GEMM2: h[64x256] @ W2'[256x256], bw prefetched one step ahead ----
    #pragma unroll
    for (int mf = 0; mf < 2; ++mf)
        #pragma unroll
        for (int nf = 0; nf < 4; ++nf) acc[mf][nf] = (f32x4){0.f, 0.f, 0.f, 0.f};

    #pragma unroll
    for (int s = 0; s < 8; ++s) {
        if (s < 7)
            #pragma unroll
            for (int nf = 0; nf < 4; ++nf)
                bwn[nf] = *(const bf16x8*)(bp2t + ((size_t)(s + 1) * 4 * 256 + nf * 16) * 8);
        bf16x8 af[2];
        #pragma unroll
        for (int mf = 0; mf < 2; ++mf) {
            int row = rbase + mf * 16 + l15;
            unsigned off = (unsigned)(row * 512 + (s * 32 + lg * 8) * 2);
            off ^= (unsigned)((row & 7) << 4);
            af[mf] = *(const bf16x8*)((char*)h_lds + off);
        }
        #pragma unroll
        for (int mf = 0; mf < 2; ++mf)
            #pragma unroll
            for (int nf = 0; nf < 4; ++nf)
                acc[mf][nf] = __builtin_amdgcn_mfma_f32_16x16x32_bf16(af[mf], bw[nf], acc[mf][nf], 0, 0, 0);
        #pragma unroll
        for (int nf = 0; nf < 4; ++nf) bw[nf] = bwn[nf];
    }

    // ---- epilogue: LN applied algebraically; direct plain stores ----
    float K1v[4], K2v[4];
    #pragma unroll
    for (int nf = 0; nf < 4; ++nf) {
        int col = wbase + nf * 16 + l15;
        K1v[nf] = K1[col]; K2v[nf] = K2[col];
    }
    #pragma unroll
    for (int mf = 0; mf < 2; ++mf)
        #pragma unroll
        for (int i = 0; i < 4; ++i) {
            int row = rbase + mf * 16 + lg * 4 + i;
            float tot = red[0][0][row] + red[0][1][row] + red[0][2][row] + red[0][3][row];
            float tq  = red[1][0][row] + red[1][1][row] + red[1][2][row] + red[1][3][row];
            float mean = tot * (1.f / 256.f);
            float var  = tq * (1.f / 256.f) - mean * mean;
            float rs = rsqrtf(var + 1e-5f);
            long row_g = block0 + row;
            float* po = out + row_g * 256 + wbase;
            #pragma unroll
            for (int nf = 0; nf < 4; ++nf)
                po[nf * 16 + l15] = rs * (acc[mf][nf][i] - mean * K1v[nf]) + K2v[nf];
        }
}

extern "C" void kernel_launch(void* const* d_in, const int* in_sizes, int n_in,
                              void* d_out, int out_size, void* d_ws, size_t ws_size,
                              hipStream_t stream) {
    const float* var_grid = (const float*)d_in[0];
    const int*   idxs     = (const int*)d_in[1];
    const float* means    = (const float*)d_in[2];
    const float* stds     = (const float*)d_in[3];
    const float* W1       = (const float*)d_in[4];
    const float* b1       = (const float*)d_in[5];
    const float* lnS      = (const float*)d_in[6];
    const float* lnO      = (const float*)d_in[7];
    const float* W2       = (const float*)d_in[8];
    const float* b2       = (const float*)d_in[9];
    float* out = (float*)d_out;

    char* ws = (char*)d_ws;
    unsigned short* bp1 = (unsigned short*)ws;               // 49152 B
    unsigned short* bp2 = (unsigned short*)(ws + 49152);     // 131072 B -> 180224
    float* latT = (float*)(ws + 180224);                     // 5768 B
    float* lonT = (float*)(ws + 186000);                     // 11520 B
    float* b1p  = (float*)(ws + 197520);                     // 1024 B
    float* K1   = (float*)(ws + 198544);                     // 1024 B
    float* K2   = (float*)(ws + 199568);                     // 1024 B (end 200592)

    prep_kernel<<<362, 256, 0, stream>>>(W1, W2, means, stds, b1, lnS, lnO, b2,
                                         bp1, bp2, latT, lonT, b1p, K1, K2);
    fused_kernel<<<NBLOCKS, 512, 0, stream>>>(var_grid, idxs, bp1, bp2, latT, lonT,
                                              b1p, K1, K2, out);
}